// Round 10
// baseline (681.705 us; speedup 1.0000x reference)
//
#include <hip/hip_runtime.h>
#include <hip/hip_bf16.h>
#include <stdint.h>

#define TOKENS 512
#define HDIM   2048
#define IDIM   1408
#define SIDIM  5632
#define NEXP   60
#define TOPK   4
#define NSLOTS (TOKENS*TOPK)   /* 2048 */
#define ROWPAD 64

// counted-vmcnt barrier primitives (T3/T4): raw s_barrier, NO vmcnt(0) drain
#define VMWAIT(N) asm volatile("s_waitcnt vmcnt(" #N ")" ::: "memory")
#define SBAR()    asm volatile("s_barrier" ::: "memory")

typedef __attribute__((ext_vector_type(8))) short bf16x8;
typedef __attribute__((ext_vector_type(4))) float f32x4;

__device__ __forceinline__ short f2bf(float f){
  uint32_t u = __float_as_uint(f);
  u = (u + 0x7fffu + ((u >> 16) & 1u)) >> 16;   // RNE
  return (short)(u & 0xffffu);
}

__device__ __forceinline__ bf16x8 pack8(float4 a, float4 b){
  bf16x8 r;
  r[0]=f2bf(a.x); r[1]=f2bf(a.y); r[2]=f2bf(a.z); r[3]=f2bf(a.w);
  r[4]=f2bf(b.x); r[5]=f2bf(b.y); r[6]=f2bf(b.z); r[7]=f2bf(b.w);
  return r;
}

__device__ __forceinline__ bf16x8 as_bf16x8(float4 v){
  union { float4 f; bf16x8 b; } u; u.f = v; return u.b;
}

__device__ __forceinline__ f32x4 zero4(){
  f32x4 z; z[0]=0.f; z[1]=0.f; z[2]=0.f; z[3]=0.f; return z;
}

__device__ __forceinline__ f32x4 mfma16(bf16x8 a, bf16x8 b, f32x4 c){
  return __builtin_amdgcn_mfma_f32_16x16x32_bf16(a, b, c, 0, 0, 0);
}

// ================== K-step-32 staged tiles (rule #21 both-sides swizzle) =====
// W tile: 64 rows x 32 fp32 = 8 KB = [64][8] float4 units, units rotated by
// row&7 (physical pu holds logical (pu-row)&7). LDS dest linear (HW), the
// permutation rides on the per-lane GLOBAL src. 2 loads/thread.
// NEW: aux=2 (CPol NT bit on gfx94x/950) — weights are a cold single-use
// stream; non-temporal marks them evict-first so they don't funnel through
// the L2 allocate/victim path. (measured R5: 0 bank conflicts w/ this scheme)
__device__ __forceinline__ void stage_w32(float4* tile, const float* __restrict__ W,
                                          int K, int k0, int tid){
  int l = tid & 63, wv = tid >> 6;
  #pragma unroll
  for (int j=0;j<2;j++){
    int u0 = j*256 + wv*64;                 // wave-uniform
    int u  = u0 + l;
    int row = u >> 3;
    int lu  = ((u & 7) - (row & 7)) & 7;
    const float* src = W + (size_t)row*K + k0 + lu*4;
    __builtin_amdgcn_global_load_lds(
        (const __attribute__((address_space(1))) void*)src,
        (__attribute__((address_space(3))) void*)(tile + u0), 16, 0, 2 /*NT*/);
  }
}

// one B-fragment (8 bf16 = k kq*8..+8 of row r)
__device__ __forceinline__ bf16x8 read_wfrag32(const float4* tile, int r, int kq){
  int rot = r & 7;
  const float4* row = tile + (size_t)r*8;
  float4 f0 = row[(2*kq     + rot) & 7];
  float4 f1 = row[(2*kq + 1 + rot) & 7];
  return pack8(f0, f1);
}

// A tile: 64 rows x 32 bf16 = 4 KB = [64][4] float4 units, rotated by row&3.
// 1 load/thread. aux=0: A IS reused across expert blocks -> keep cached.
__device__ __forceinline__ void stage_a32(float4* tile, const short* __restrict__ Arows,
                                          int K, int k0, int tid){
  int l = tid & 63, wv = tid >> 6;
  int u0 = wv*64;
  int u  = u0 + l;
  int row = u >> 2;
  int lu  = ((u & 3) - (row & 3)) & 3;
  const short* src = Arows + (size_t)row*K + k0 + lu*8;
  __builtin_amdgcn_global_load_lds(
      (const __attribute__((address_space(1))) void*)src,
      (__attribute__((address_space(3))) void*)(tile + u0), 16, 0, 0);
}

__device__ __forceinline__ void read_afrag32(const float4* tile, int c16, int kq,
                                             bf16x8* av){
  #pragma unroll
  for (int mf=0; mf<4; mf++){
    int row = c16 + 16*mf;
    av[mf] = as_bf16x8(tile[(size_t)row*4 + ((kq + row) & 3)]);
  }
}

// ---------------- router ------------------------------------------------------
__global__ __launch_bounds__(64) void router_kernel(
    const float* __restrict__ x, const float* __restrict__ rw,
    const float* __restrict__ egw, int* __restrict__ topk_idx,
    float* __restrict__ topk_w, float* __restrict__ gates,
    int* __restrict__ counts)
{
  int t = blockIdx.x;
  int lane = threadIdx.x;
  const float* xr = x + (size_t)t*HDIM;
  float xv[HDIM/64];
  #pragma unroll
  for (int i=0;i<HDIM/64;i++) xv[i] = xr[lane + 64*i];

  float mylogit = -1e30f;
  for (int e=0;e<NEXP;e++){
    const float* w = rw + (size_t)e*HDIM;
    float acc = 0.f;
    #pragma unroll
    for (int i=0;i<HDIM/64;i++) acc += xv[i]*w[lane+64*i];
    #pragma unroll
    for (int s=32;s>0;s>>=1) acc += __shfl_xor(acc, s);
    if (lane == e) mylogit = acc;
  }
  {
    float acc = 0.f;
    #pragma unroll
    for (int i=0;i<HDIM/64;i++) acc += xv[i]*egw[lane+64*i];
    #pragma unroll
    for (int s=32;s>0;s>>=1) acc += __shfl_xor(acc, s);
    if (lane == 0) gates[t] = 1.f/(1.f + __expf(-acc));
  }
  float m = mylogit;
  #pragma unroll
  for (int s=32;s>0;s>>=1) m = fmaxf(m, __shfl_xor(m, s));
  float p = (lane < NEXP) ? __expf(mylogit - m) : 0.f;
  float sum = p;
  #pragma unroll
  for (int s=32;s>0;s>>=1) sum += __shfl_xor(sum, s);
  float prob = p / sum;
  for (int k=0;k<TOPK;k++){
    float v = prob; int idx = lane;
    #pragma unroll
    for (int s=32;s>0;s>>=1){
      float ov = __shfl_xor(v, s); int oi = __shfl_xor(idx, s);
      if (ov > v || (ov == v && oi < idx)){ v = ov; idx = oi; }
    }
    if (lane == 0){
      topk_idx[t*TOPK+k] = idx;
      topk_w[t*TOPK+k]  = v;
      atomicAdd(&counts[idx], 1);
    }
    if (lane == idx) prob = -1e30f;
  }
}

__global__ void prefix_kernel(const int* __restrict__ counts, int* __restrict__ offsets)
{
  if (threadIdx.x == 0){
    int acc = 0;
    for (int e=0;e<NEXP;e++){ offsets[e] = acc; acc += counts[e]; }
    offsets[NEXP] = acc;
  }
}

__global__ __launch_bounds__(256) void scatter_kernel(
    const float* __restrict__ x, const int* __restrict__ topk_idx,
    const int* __restrict__ offsets, int* __restrict__ fill,
    int* __restrict__ slot_of, __hip_bfloat16* __restrict__ xg,
    __hip_bfloat16* __restrict__ xb)
{
  int t = blockIdx.x, tid = threadIdx.x;
  __shared__ int sl[TOPK];
  if (tid == 0){
    for (int k=0;k<TOPK;k++){
      int e = topk_idx[t*TOPK+k];
      int pos = atomicAdd(&fill[e], 1);
      int s = offsets[e] + pos;
      slot_of[t*TOPK+k] = s;
      sl[k] = s;
    }
  }
  __syncthreads();
  const float4* xr = (const float4*)(x + (size_t)t*HDIM);
  float4 v0 = xr[tid*2], v1 = xr[tid*2+1];
  bf16x8 b = pack8(v0, v1);
  *(bf16x8*)((short*)xb + (size_t)t*HDIM + tid*8) = b;
  #pragma unroll
  for (int k=0;k<TOPK;k++)
    *(bf16x8*)((short*)xg + (size_t)sl[k]*HDIM + tid*8) = b;
}

// =============== combined gate+up GEMM (R5 structure + NT W-loads) ===========
// grid = 2024 blocks (8 XCDs x 253). per-XCD: pos<88 -> shared (m-tile=xcd),
// else expert q = xcd*165 + pos-88, e=q/22, bx=q%22 (same-expert contiguous).
// LDS 40 KB: G0,G1,U0,U1 (8 KB) + A0,A1 (4 KB) -> 4 blocks/CU. VMWAIT(5).
__global__ __launch_bounds__(256, 4) void gateup_all(
    const float* __restrict__ gW_e, const float* __restrict__ uW_e,
    const __hip_bfloat16* __restrict__ A_e, __hip_bfloat16* __restrict__ out_e,
    const float* __restrict__ gW_s, const float* __restrict__ uW_s,
    const __hip_bfloat16* __restrict__ A_s, __hip_bfloat16* __restrict__ out_s,
    const int* __restrict__ offsets)
{
  extern __shared__ __align__(16) char smem[];
  float4* G0 = (float4*)smem;
  float4* G1 = G0 + 512;
  float4* U0 = G1 + 512;
  float4* U1 = U0 + 512;
  float4* A0 = U1 + 512;
  float4* A1 = A0 + 256;

  int bid = blockIdx.x;
  int xcd = bid & 7, pos = bid >> 3;
  const float *Wg, *Wu; const short *Abase; short *outp;
  int NI, bx, m_start, m_end;
  if (pos < 88){                       // shared expert
    bx = pos;
    Wg = gW_s; Wu = uW_s; Abase = (const short*)A_s; outp = (short*)out_s;
    NI = SIDIM;
    m_start = xcd*64; m_end = m_start + 64;
  } else {                             // routed experts
    int q = xcd*165 + (pos - 88);
    int e = q/22; bx = q - e*22;
    size_t wo = (size_t)e * IDIM * HDIM;
    Wg = gW_e + wo; Wu = uW_e + wo;
    Abase = (const short*)A_e; outp = (short*)out_e;
    NI = IDIM;
    m_start = offsets[e]; m_end = offsets[e+1];
  }
  if (m_start >= m_end) return;
  const int K = HDIM;

  int tid  = threadIdx.x;
  int lane = tid & 63;
  int wv   = tid >> 6;
  int c16 = lane & 15, kq = lane >> 4;
  int wrow = bx*64 + wv*16 + c16;
  int r    = wv*16 + c16;
  const float* WgT = Wg + (size_t)(bx*64)*K;
  const float* WuT = Wu + (size_t)(bx*64)*K;

  for (int m0 = m_start; m0 < m_end; m0 += 64){
    int mrem = m_end - m0;
    const short* Ar = Abase + (size_t)m0*K;
    f32x4 accg[4], accu[4];
    #pragma unroll
    for (int i=0;i<4;i++){ accg[i] = zero4(); accu[i] = zero4(); }

    stage_w32(G0, WgT, K, 0, tid);
    stage_w32(U0, WuT, K, 0, tid);
    stage_a32(A0, Ar,  K, 0, tid);

    for (int k0 = 0; k0 < K; k0 += 64){
      stage_w32(G1, WgT, K, k0+32, tid);
      stage_w32(U1, WuT, K, k0+32, tid);
      stage_a32(A1, Ar,  K, k0+32, tid);
      VMWAIT(5); SBAR();
      {
        bf16x8 av[4];
        read_afrag32(A0, c16, kq, av);
        bf16x8 bg = read_wfrag32(G0, r, kq);
        bf16x8 bu = read_wfrag32(U0, r, kq);
        #pragma unroll
        for (int mf=0; mf<4; mf++){
          accg[mf] = mfma16(av[mf], bg, accg[mf]);
          accu[mf] = mfma16(av[mf], bu, accu[mf]);
        }
      }
      SBAR();
      if (k0 + 64 < K){
        stage_w32(G0, WgT, K, k0+64, tid);
        stage_w32(U0, WuT, K, k0+64, tid);
        stage_a32(A0, Ar,  K, k0+64, tid);
        VMWAIT(5);
      } else {
        VMWAIT(0);
      }
      SBAR();
      {
        bf16x8 av[4];
        read_afrag32(A1, c16, kq, av);
        bf16x8 bg = read_wfrag32(G1, r, kq);
        bf16x8 bu = read_wfrag32(U1, r, kq);
        #pragma unroll
        for (int mf=0; mf<4; mf++){
          accg[mf] = mfma16(av[mf], bg, accg[mf]);
          accu[mf] = mfma16(av[mf], bu, accu[mf]);
        }
      }
      SBAR();
    }

    #pragma unroll
    for (int mf=0; mf<4; mf++){
      #pragma unroll
      for (int j=0;j<4;j++){
        int mrow = mf*16 + kq*4 + j;
        if (mrow < mrem){
          float g = accg[mf][j], u = accu[mf][j];
          float s = g * u / (1.f + __expf(-g));
          outp[(size_t)(m0+mrow)*NI + wrow] = f2bf(s);
        }
      }
    }
  }
}

// =============== combined down GEMM (3-deep pipeline + NT W-loads) ===========
// grid = 2176 blocks (8 x 272). per-XCD: pos<32 -> shared (m-tile=xcd,
// K=SIDIM, heavy: first), else expert q = xcd*240+pos-32, e=q/32.
// LDS 36 KB: W slots x3 (8 KB) + A slots x3 (4 KB) -> 4 blocks/CU.
// Ledger: stage tile t+2, VMWAIT(6) => tile t landed, t+1 AND t+2 in flight.
__global__ __launch_bounds__(256, 4) void down_all(
    const float* __restrict__ W_e, const __hip_bfloat16* __restrict__ A_e,
    float* __restrict__ out_e,
    const float* __restrict__ W_s, const __hip_bfloat16* __restrict__ A_s,
    float* __restrict__ out_s,
    const int* __restrict__ offsets)
{
  extern __shared__ __align__(16) char smem[];
  float4* Wb = (float4*)smem;          // 3 x 512 float4
  float4* Ab = Wb + 3*512;             // 3 x 256 float4

  int bid = blockIdx.x;
  int xcd = bid & 7, pos = bid >> 3;
  const float* W; const short* Abase; float* outp;
  int K, bx, m_start, m_end;
  if (pos < 32){                       // shared expert (long blocks first)
    bx = pos;
    W = W_s; Abase = (const short*)A_s; outp = out_s; K = SIDIM;
    m_start = xcd*64; m_end = m_start + 64;
  } else {
    int q = xcd*240 + (pos - 32);
    int e = q >> 5; bx = q & 31;
    W = W_e + (size_t)e * HDIM * IDIM;
    Abase = (const short*)A_e; outp = out_e; K = IDIM;
    m_start = offsets[e]; m_end = offsets[e+1];
  }
  if (m_start >= m_end) return;

  int tid  = threadIdx.x;
  int lane = tid & 63;
  int wv   = tid >> 6;
  int c16 = lane & 15, kq = lane >> 4;
  int wrow = bx*64 + wv*16 + c16;
  int r    = wv*16 + c16;
  const float* WT = W + (size_t)(bx*64)*K;
  int np = K >> 5;                     // phases of 32 k-floats

  for (int m0 = m_start; m0 < m_end; m0 += 64){
    int mrem = m_end - m0;
    const short* Ar = Abase + (size_t)m0*K;
    f32x4 acc[4];
    #pragma unroll
    for (int i=0;i<4;i++) acc[i] = zero4();

    // prologue: tiles 0 and 1 in flight (6 loads/thread)
    stage_w32(Wb,       WT, K, 0,  tid);
    stage_a32(Ab,       Ar, K, 0,  tid);
    stage_w32(Wb + 512, WT, K, 32, tid);
    stage_a32(Ab + 256, Ar, K, 32, tid);

    int cs = 0, ss = 2;                // compute slot (p%3), stage slot ((p+2)%3)
    for (int p = 0; p < np; ++p){
      if (p + 2 < np){
        stage_w32(Wb + ss*512, WT, K, (p+2) << 5, tid);
        stage_a32(Ab + ss*256, Ar, K, (p+2) << 5, tid);
        VMWAIT(6);                     // tile p landed; p+1, p+2 in flight
      } else if (p + 1 < np){
        VMWAIT(3);                     // tile p landed; p+1 in flight
      } else {
        VMWAIT(0);                     // last tile
      }
      SBAR();
      {
        bf16x8 av[4];
        read_afrag32(Ab + cs*256, c16, kq, av);
        bf16x8 b = read_wfrag32(Wb + cs*512, r, kq);
        #pragma unroll
        for (int mf=0; mf<4; mf++)
          acc[mf] = mfma16(av[mf], b, acc[mf]);
      }
      SBAR();                          // all reads of slot cs done before restage
      cs = (cs == 2) ? 0 : cs + 1;
      ss = (ss == 2) ? 0 : ss + 1;
    }

    #pragma unroll
    for (int mf=0; mf<4; mf++){
      #pragma unroll
      for (int j=0;j<4;j++){
        int mrow = mf*16 + kq*4 + j;
        if (mrow < mrem)
          outp[(size_t)(m0+mrow)*HDIM + wrow] = acc[mf][j];
      }
    }
  }
}

// ---------------- final combine ----------------------------------------------
__global__ __launch_bounds__(256) void combine_kernel(
    const float* __restrict__ dslot, const float* __restrict__ shdown,
    const int* __restrict__ slot_of, const float* __restrict__ topw,
    const float* __restrict__ gates, float* __restrict__ out)
{
  int t = blockIdx.x, tid = threadIdx.x;
  int4  sl = ((const int4*)slot_of)[t];
  float4 w = ((const float4*)topw)[t];
  float sg = gates[t];
  const float* r0 = dslot + (size_t)sl.x*HDIM;
  const float* r1 = dslot + (size_t)sl.y*HDIM;
  const float* r2 = dslot + (size_t)sl.z*HDIM;
  const float* r3 = dslot + (size_t)sl.w*HDIM;
  const float* rs = shdown + (size_t)t*HDIM;
  float* o = out + (size_t)t*HDIM;
  #pragma unroll
  for (int it=0; it<HDIM/(256*4); ++it){
    int h = (tid + it*256) * 4;
    float4 a0 = *(const float4*)(r0+h);
    float4 a1 = *(const float4*)(r1+h);
    float4 a2 = *(const float4*)(r2+h);
    float4 a3 = *(const float4*)(r3+h);
    float4 as = *(const float4*)(rs+h);
    float4 r;
    r.x = w.x*a0.x + w.y*a1.x + w.z*a2.x + w.w*a3.x + sg*as.x;
    r.y = w.x*a0.y + w.y*a1.y + w.z*a2.y + w.w*a3.y + sg*as.y;
    r.z = w.x*a0.z + w.y*a1.z + w.z*a2.z + w.w*a3.z + sg*as.z;
    r.w = w.x*a0.w + w.y*a1.w + w.z*a2.w + w.w*a3.w + sg*as.w;
    *(float4*)(o+h) = r;
  }
}

extern "C" void kernel_launch(void* const* d_in, const int* in_sizes, int n_in,
                              void* d_out, int out_size, void* d_ws, size_t ws_size,
                              hipStream_t stream)
{
  const float* x         = (const float*)d_in[0];
  const float* router_w  = (const float*)d_in[1];
  const float* gate_w    = (const float*)d_in[2];
  const float* up_w      = (const float*)d_in[3];
  const float* down_w    = (const float*)d_in[4];
  const float* sh_gate_w = (const float*)d_in[5];
  const float* sh_up_w   = (const float*)d_in[6];
  const float* sh_down_w = (const float*)d_in[7];
  const float* eg_w      = (const float*)d_in[8];

  char* p = (char*)d_ws;
  auto alloc = [&](size_t bytes)->char*{
    char* r = p; p += (bytes + 255) & ~(size_t)255; return r;
  };
  int*   counts   = (int*)  alloc(NEXP*4);
  int*   fill     = (int*)  alloc(NEXP*4);
  int*   offsets  = (int*)  alloc((NEXP+1)*4);
  int*   topk_idx = (int*)  alloc(NSLOTS*4);
  float* topk_w   = (float*)alloc(NSLOTS*4);
  int*   slot_of  = (int*)  alloc(NSLOTS*4);
  float* gates    = (float*)alloc(TOKENS*4);
  __hip_bfloat16* xb    = (__hip_bfloat16*)alloc((size_t)TOKENS*HDIM*2);
  __hip_bfloat16* xg    = (__hip_bfloat16*)alloc((size_t)(NSLOTS+ROWPAD)*HDIM*2);
  __hip_bfloat16* act   = (__hip_bfloat16*)alloc((size_t)(NSLOTS+ROWPAD)*IDIM*2);
  __hip_bfloat16* shact = (__hip_bfloat16*)alloc((size_t)TOKENS*SIDIM*2);
  float* dslot  = (float*)alloc((size_t)NSLOTS*HDIM*4);
  float* shdown = (float*)alloc((size_t)TOKENS*HDIM*4);
  if ((size_t)(p - (char*)d_ws) > ws_size) return;

  hipMemsetAsync(counts, 0, NEXP*4, stream);
  hipMemsetAsync(fill,   0, NEXP*4, stream);

  router_kernel <<<TOKENS, 64, 0, stream>>>(x, router_w, eg_w, topk_idx, topk_w, gates, counts);
  prefix_kernel <<<1, 64, 0, stream>>>(counts, offsets);
  scatter_kernel<<<TOKENS, 256, 0, stream>>>(x, topk_idx, offsets, fill, slot_of, xg, xb);

  // combined gate+up: 8 XCDs x (88 shared + 165 expert) = 2024 blocks
  gateup_all<<<2024, 256, 40*1024, stream>>>(
      gate_w, up_w, xg, act,
      sh_gate_w, sh_up_w, xb, shact, offsets);

  // combined down: 8 XCDs x (32 shared + 240 expert) = 2176 blocks, 3-deep
  down_all<<<2176, 256, 36*1024, stream>>>(
      down_w, act, dslot,
      sh_down_w, shact, shdown, offsets);

  combine_kernel<<<TOKENS, 256, 0, stream>>>(dslot, shdown, slot_of, topk_w, gates, (float*)d_out);
}

// Round 11
// 647.740 us; speedup vs baseline: 1.0524x; 1.0524x over previous
//
#include <hip/hip_runtime.h>
#include <hip/hip_bf16.h>
#include <stdint.h>

#define TOKENS 512
#define HDIM   2048
#define IDIM   1408
#define SIDIM  5632
#define NEXP   60
#define TOPK   4
#define NSLOTS (TOKENS*TOPK)   /* 2048 */
#define ROWPAD 64

// counted-vmcnt barrier primitives (T3/T4): raw s_barrier, NO vmcnt(0) drain
#define VMWAIT(N) asm volatile("s_waitcnt vmcnt(" #N ")" ::: "memory")
#define SBAR()    asm volatile("s_barrier" ::: "memory")

typedef __attribute__((ext_vector_type(8))) short bf16x8;
typedef __attribute__((ext_vector_type(4))) float f32x4;

__device__ __forceinline__ short f2bf(float f){
  uint32_t u = __float_as_uint(f);
  u = (u + 0x7fffu + ((u >> 16) & 1u)) >> 16;   // RNE
  return (short)(u & 0xffffu);
}

__device__ __forceinline__ bf16x8 pack8(float4 a, float4 b){
  bf16x8 r;
  r[0]=f2bf(a.x); r[1]=f2bf(a.y); r[2]=f2bf(a.z); r[3]=f2bf(a.w);
  r[4]=f2bf(b.x); r[5]=f2bf(b.y); r[6]=f2bf(b.z); r[7]=f2bf(b.w);
  return r;
}

__device__ __forceinline__ bf16x8 as_bf16x8(float4 v){
  union { float4 f; bf16x8 b; } u; u.f = v; return u.b;
}

__device__ __forceinline__ f32x4 zero4(){
  f32x4 z; z[0]=0.f; z[1]=0.f; z[2]=0.f; z[3]=0.f; return z;
}

__device__ __forceinline__ f32x4 mfma16(bf16x8 a, bf16x8 b, f32x4 c){
  return __builtin_amdgcn_mfma_f32_16x16x32_bf16(a, b, c, 0, 0, 0);
}

// ================== K-step-32 staged tiles (rule #21 both-sides swizzle) =====
// W tile: 64 rows x 32 fp32 = 8 KB = [64][8] float4 units, units rotated by
// row&7 (physical pu holds logical (pu-row)&7). LDS dest linear (HW), the
// permutation rides on the per-lane GLOBAL src. 2 loads/thread. aux=0
// (R10 measured: NT bypass costs ~5% -- L3 serves shared-W re-reads).
__device__ __forceinline__ void stage_w32(float4* tile, const float* __restrict__ W,
                                          int K, int k0, int tid){
  int l = tid & 63, wv = tid >> 6;
  #pragma unroll
  for (int j=0;j<2;j++){
    int u0 = j*256 + wv*64;                 // wave-uniform
    int u  = u0 + l;
    int row = u >> 3;
    int lu  = ((u & 7) - (row & 7)) & 7;
    const float* src = W + (size_t)row*K + k0 + lu*4;
    __builtin_amdgcn_global_load_lds(
        (const __attribute__((address_space(1))) void*)src,
        (__attribute__((address_space(3))) void*)(tile + u0), 16, 0, 0);
  }
}

// one B-fragment (8 bf16 = k kq*8..+8 of row r)
__device__ __forceinline__ bf16x8 read_wfrag32(const float4* tile, int r, int kq){
  int rot = r & 7;
  const float4* row = tile + (size_t)r*8;
  float4 f0 = row[(2*kq     + rot) & 7];
  float4 f1 = row[(2*kq + 1 + rot) & 7];
  return pack8(f0, f1);
}

// A tile: 64 rows x 32 bf16 = 4 KB = [64][4] float4 units, rotated by row&3.
// 1 load/thread.
__device__ __forceinline__ void stage_a32(float4* tile, const short* __restrict__ Arows,
                                          int K, int k0, int tid){
  int l = tid & 63, wv = tid >> 6;
  int u0 = wv*64;
  int u  = u0 + l;
  int row = u >> 2;
  int lu  = ((u & 3) - (row & 3)) & 3;
  const short* src = Arows + (size_t)row*K + k0 + lu*8;
  __builtin_amdgcn_global_load_lds(
      (const __attribute__((address_space(1))) void*)src,
      (__attribute__((address_space(3))) void*)(tile + u0), 16, 0, 0);
}

__device__ __forceinline__ void read_afrag32(const float4* tile, int c16, int kq,
                                             bf16x8* av){
  #pragma unroll
  for (int mf=0; mf<4; mf++){
    int row = c16 + 16*mf;
    av[mf] = as_bf16x8(tile[(size_t)row*4 + ((kq + row) & 3)]);
  }
}

// ---------------- router ------------------------------------------------------
__global__ __launch_bounds__(64) void router_kernel(
    const float* __restrict__ x, const float* __restrict__ rw,
    const float* __restrict__ egw, int* __restrict__ topk_idx,
    float* __restrict__ topk_w, float* __restrict__ gates,
    int* __restrict__ counts)
{
  int t = blockIdx.x;
  int lane = threadIdx.x;
  const float* xr = x + (size_t)t*HDIM;
  float xv[HDIM/64];
  #pragma unroll
  for (int i=0;i<HDIM/64;i++) xv[i] = xr[lane + 64*i];

  float mylogit = -1e30f;
  for (int e=0;e<NEXP;e++){
    const float* w = rw + (size_t)e*HDIM;
    float acc = 0.f;
    #pragma unroll
    for (int i=0;i<HDIM/64;i++) acc += xv[i]*w[lane+64*i];
    #pragma unroll
    for (int s=32;s>0;s>>=1) acc += __shfl_xor(acc, s);
    if (lane == e) mylogit = acc;
  }
  {
    float acc = 0.f;
    #pragma unroll
    for (int i=0;i<HDIM/64;i++) acc += xv[i]*egw[lane+64*i];
    #pragma unroll
    for (int s=32;s>0;s>>=1) acc += __shfl_xor(acc, s);
    if (lane == 0) gates[t] = 1.f/(1.f + __expf(-acc));
  }
  float m = mylogit;
  #pragma unroll
  for (int s=32;s>0;s>>=1) m = fmaxf(m, __shfl_xor(m, s));
  float p = (lane < NEXP) ? __expf(mylogit - m) : 0.f;
  float sum = p;
  #pragma unroll
  for (int s=32;s>0;s>>=1) sum += __shfl_xor(sum, s);
  float prob = p / sum;
  for (int k=0;k<TOPK;k++){
    float v = prob; int idx = lane;
    #pragma unroll
    for (int s=32;s>0;s>>=1){
      float ov = __shfl_xor(v, s); int oi = __shfl_xor(idx, s);
      if (ov > v || (ov == v && oi < idx)){ v = ov; idx = oi; }
    }
    if (lane == 0){
      topk_idx[t*TOPK+k] = idx;
      topk_w[t*TOPK+k]  = v;
      atomicAdd(&counts[idx], 1);
    }
    if (lane == idx) prob = -1e30f;
  }
}

// ---------------- scatter (+ folded prefix scan, proven in R6 mega) ----------
__global__ __launch_bounds__(256) void scatter_kernel(
    const float* __restrict__ x, const int* __restrict__ topk_idx,
    const int* __restrict__ counts, int* __restrict__ offsets,
    int* __restrict__ fill, int* __restrict__ slot_of,
    __hip_bfloat16* __restrict__ xg, __hip_bfloat16* __restrict__ xb)
{
  int t = blockIdx.x, tid = threadIdx.x;
  if (tid == 0){
    int e0 = topk_idx[t*TOPK+0], e1 = topk_idx[t*TOPK+1];
    int e2 = topk_idx[t*TOPK+2], e3 = topk_idx[t*TOPK+3];
    int o0=0,o1=0,o2=0,o3=0, acc=0;
    for (int e=0;e<NEXP;e++){
      int c = counts[e];
      if (t == 0) offsets[e] = acc;           // block 0 publishes prefix
      if (e==e0) o0=acc; if (e==e1) o1=acc;
      if (e==e2) o2=acc; if (e==e3) o3=acc;
      acc += c;
    }
    if (t == 0) offsets[NEXP] = acc;
    slot_of[t*TOPK+0] = o0 + atomicAdd(&fill[e0],1);
    slot_of[t*TOPK+1] = o1 + atomicAdd(&fill[e1],1);
    slot_of[t*TOPK+2] = o2 + atomicAdd(&fill[e2],1);
    slot_of[t*TOPK+3] = o3 + atomicAdd(&fill[e3],1);
  }
  __syncthreads();
  int4 sl = ((const int4*)slot_of)[t];
  const float4* xr = (const float4*)(x + (size_t)t*HDIM);
  float4 v0 = xr[tid*2], v1 = xr[tid*2+1];
  bf16x8 b = pack8(v0, v1);
  *(bf16x8*)((short*)xb + (size_t)t*HDIM + tid*8) = b;
  *(bf16x8*)((short*)xg + (size_t)sl.x*HDIM + tid*8) = b;
  *(bf16x8*)((short*)xg + (size_t)sl.y*HDIM + tid*8) = b;
  *(bf16x8*)((short*)xg + (size_t)sl.z*HDIM + tid*8) = b;
  *(bf16x8*)((short*)xg + (size_t)sl.w*HDIM + tid*8) = b;
}

// =============== combined gate+up GEMM (R5/R9 exact structure) ===============
// grid = 2024 blocks (8 XCDs x 253). per-XCD: pos<88 -> shared (m-tile=xcd),
// else expert q = xcd*165 + pos-88, e=q/22, bx=q%22 (same-expert contiguous).
// LDS 40 KB: G0,G1,U0,U1 (8 KB) + A0,A1 (4 KB) -> 4 blocks/CU. VMWAIT(5).
__global__ __launch_bounds__(256, 4) void gateup_all(
    const float* __restrict__ gW_e, const float* __restrict__ uW_e,
    const __hip_bfloat16* __restrict__ A_e, __hip_bfloat16* __restrict__ out_e,
    const float* __restrict__ gW_s, const float* __restrict__ uW_s,
    const __hip_bfloat16* __restrict__ A_s, __hip_bfloat16* __restrict__ out_s,
    const int* __restrict__ offsets)
{
  extern __shared__ __align__(16) char smem[];
  float4* G0 = (float4*)smem;
  float4* G1 = G0 + 512;
  float4* U0 = G1 + 512;
  float4* U1 = U0 + 512;
  float4* A0 = U1 + 512;
  float4* A1 = A0 + 256;

  int bid = blockIdx.x;
  int xcd = bid & 7, pos = bid >> 3;
  const float *Wg, *Wu; const short *Abase; short *outp;
  int NI, bx, m_start, m_end;
  if (pos < 88){                       // shared expert
    bx = pos;
    Wg = gW_s; Wu = uW_s; Abase = (const short*)A_s; outp = (short*)out_s;
    NI = SIDIM;
    m_start = xcd*64; m_end = m_start + 64;
  } else {                             // routed experts
    int q = xcd*165 + (pos - 88);
    int e = q/22; bx = q - e*22;
    size_t wo = (size_t)e * IDIM * HDIM;
    Wg = gW_e + wo; Wu = uW_e + wo;
    Abase = (const short*)A_e; outp = (short*)out_e;
    NI = IDIM;
    m_start = offsets[e]; m_end = offsets[e+1];
  }
  if (m_start >= m_end) return;
  const int K = HDIM;

  int tid  = threadIdx.x;
  int lane = tid & 63;
  int wv   = tid >> 6;
  int c16 = lane & 15, kq = lane >> 4;
  int wrow = bx*64 + wv*16 + c16;
  int r    = wv*16 + c16;
  const float* WgT = Wg + (size_t)(bx*64)*K;
  const float* WuT = Wu + (size_t)(bx*64)*K;

  for (int m0 = m_start; m0 < m_end; m0 += 64){
    int mrem = m_end - m0;
    const short* Ar = Abase + (size_t)m0*K;
    f32x4 accg[4], accu[4];
    #pragma unroll
    for (int i=0;i<4;i++){ accg[i] = zero4(); accu[i] = zero4(); }

    stage_w32(G0, WgT, K, 0, tid);
    stage_w32(U0, WuT, K, 0, tid);
    stage_a32(A0, Ar,  K, 0, tid);

    for (int k0 = 0; k0 < K; k0 += 64){
      stage_w32(G1, WgT, K, k0+32, tid);
      stage_w32(U1, WuT, K, k0+32, tid);
      stage_a32(A1, Ar,  K, k0+32, tid);
      VMWAIT(5); SBAR();
      {
        bf16x8 av[4];
        read_afrag32(A0, c16, kq, av);
        bf16x8 bg = read_wfrag32(G0, r, kq);
        bf16x8 bu = read_wfrag32(U0, r, kq);
        #pragma unroll
        for (int mf=0; mf<4; mf++){
          accg[mf] = mfma16(av[mf], bg, accg[mf]);
          accu[mf] = mfma16(av[mf], bu, accu[mf]);
        }
      }
      SBAR();
      if (k0 + 64 < K){
        stage_w32(G0, WgT, K, k0+64, tid);
        stage_w32(U0, WuT, K, k0+64, tid);
        stage_a32(A0, Ar,  K, k0+64, tid);
        VMWAIT(5);
      } else {
        VMWAIT(0);
      }
      SBAR();
      {
        bf16x8 av[4];
        read_afrag32(A1, c16, kq, av);
        bf16x8 bg = read_wfrag32(G1, r, kq);
        bf16x8 bu = read_wfrag32(U1, r, kq);
        #pragma unroll
        for (int mf=0; mf<4; mf++){
          accg[mf] = mfma16(av[mf], bg, accg[mf]);
          accu[mf] = mfma16(av[mf], bu, accu[mf]);
        }
      }
      SBAR();
    }

    #pragma unroll
    for (int mf=0; mf<4; mf++){
      #pragma unroll
      for (int j=0;j<4;j++){
        int mrow = mf*16 + kq*4 + j;
        if (mrow < mrem){
          float g = accg[mf][j], u = accu[mf][j];
          float s = g * u / (1.f + __expf(-g));
          outp[(size_t)(m0+mrow)*NI + wrow] = f2bf(s);
        }
      }
    }
  }
}

// =============== combined down GEMM (R9 3-deep pipeline, aux=0) ==============
// grid = 2176 blocks (8 x 272). per-XCD: pos<32 -> shared (m-tile=xcd,
// K=SIDIM, heavy: first), else expert q = xcd*240+pos-32, e=q/32.
// LDS 36 KB: W slots x3 (8 KB) + A slots x3 (4 KB) -> 4 blocks/CU.
// Ledger: stage tile t+2, VMWAIT(6) => tile t landed, t+1 AND t+2 in flight.
__global__ __launch_bounds__(256, 4) void down_all(
    const float* __restrict__ W_e, const __hip_bfloat16* __restrict__ A_e,
    float* __restrict__ out_e,
    const float* __restrict__ W_s, const __hip_bfloat16* __restrict__ A_s,
    float* __restrict__ out_s,
    const int* __restrict__ offsets)
{
  extern __shared__ __align__(16) char smem[];
  float4* Wb = (float4*)smem;          // 3 x 512 float4
  float4* Ab = Wb + 3*512;             // 3 x 256 float4

  int bid = blockIdx.x;
  int xcd = bid & 7, pos = bid >> 3;
  const float* W; const short* Abase; float* outp;
  int K, bx, m_start, m_end;
  if (pos < 32){                       // shared expert (long blocks first)
    bx = pos;
    W = W_s; Abase = (const short*)A_s; outp = out_s; K = SIDIM;
    m_start = xcd*64; m_end = m_start + 64;
  } else {
    int q = xcd*240 + (pos - 32);
    int e = q >> 5; bx = q & 31;
    W = W_e + (size_t)e * HDIM * IDIM;
    Abase = (const short*)A_e; outp = out_e; K = IDIM;
    m_start = offsets[e]; m_end = offsets[e+1];
  }
  if (m_start >= m_end) return;

  int tid  = threadIdx.x;
  int lane = tid & 63;
  int wv   = tid >> 6;
  int c16 = lane & 15, kq = lane >> 4;
  int wrow = bx*64 + wv*16 + c16;
  int r    = wv*16 + c16;
  const float* WT = W + (size_t)(bx*64)*K;
  int np = K >> 5;                     // phases of 32 k-floats

  for (int m0 = m_start; m0 < m_end; m0 += 64){
    int mrem = m_end - m0;
    const short* Ar = Abase + (size_t)m0*K;
    f32x4 acc[4];
    #pragma unroll
    for (int i=0;i<4;i++) acc[i] = zero4();

    // prologue: tiles 0 and 1 in flight (6 loads/thread)
    stage_w32(Wb,       WT, K, 0,  tid);
    stage_a32(Ab,       Ar, K, 0,  tid);
    stage_w32(Wb + 512, WT, K, 32, tid);
    stage_a32(Ab + 256, Ar, K, 32, tid);

    int cs = 0, ss = 2;                // compute slot (p%3), stage slot ((p+2)%3)
    for (int p = 0; p < np; ++p){
      if (p + 2 < np){
        stage_w32(Wb + ss*512, WT, K, (p+2) << 5, tid);
        stage_a32(Ab + ss*256, Ar, K, (p+2) << 5, tid);
        VMWAIT(6);                     // tile p landed; p+1, p+2 in flight
      } else if (p + 1 < np){
        VMWAIT(3);                     // tile p landed; p+1 in flight
      } else {
        VMWAIT(0);                     // last tile
      }
      SBAR();
      {
        bf16x8 av[4];
        read_afrag32(Ab + cs*256, c16, kq, av);
        bf16x8 b = read_wfrag32(Wb + cs*512, r, kq);
        #pragma unroll
        for (int mf=0; mf<4; mf++)
          acc[mf] = mfma16(av[mf], b, acc[mf]);
      }
      SBAR();                          // all reads of slot cs done before restage
      cs = (cs == 2) ? 0 : cs + 1;
      ss = (ss == 2) ? 0 : ss + 1;
    }

    #pragma unroll
    for (int mf=0; mf<4; mf++){
      #pragma unroll
      for (int j=0;j<4;j++){
        int mrow = mf*16 + kq*4 + j;
        if (mrow < mrem)
          outp[(size_t)(m0+mrow)*HDIM + wrow] = acc[mf][j];
      }
    }
  }
}

// ---------------- final combine ----------------------------------------------
__global__ __launch_bounds__(256) void combine_kernel(
    const float* __restrict__ dslot, const float* __restrict__ shdown,
    const int* __restrict__ slot_of, const float* __restrict__ topw,
    const float* __restrict__ gates, float* __restrict__ out)
{
  int t = blockIdx.x, tid = threadIdx.x;
  int4  sl = ((const int4*)slot_of)[t];
  float4 w = ((const float4*)topw)[t];
  float sg = gates[t];
  const float* r0 = dslot + (size_t)sl.x*HDIM;
  const float* r1 = dslot + (size_t)sl.y*HDIM;
  const float* r2 = dslot + (size_t)sl.z*HDIM;
  const float* r3 = dslot + (size_t)sl.w*HDIM;
  const float* rs = shdown + (size_t)t*HDIM;
  float* o = out + (size_t)t*HDIM;
  #pragma unroll
  for (int it=0; it<HDIM/(256*4); ++it){
    int h = (tid + it*256) * 4;
    float4 a0 = *(const float4*)(r0+h);
    float4 a1 = *(const float4*)(r1+h);
    float4 a2 = *(const float4*)(r2+h);
    float4 a3 = *(const float4*)(r3+h);
    float4 as = *(const float4*)(rs+h);
    float4 r;
    r.x = w.x*a0.x + w.y*a1.x + w.z*a2.x + w.w*a3.x + sg*as.x;
    r.y = w.x*a0.y + w.y*a1.y + w.z*a2.y + w.w*a3.y + sg*as.y;
    r.z = w.x*a0.z + w.y*a1.z + w.z*a2.z + w.w*a3.z + sg*as.z;
    r.w = w.x*a0.w + w.y*a1.w + w.z*a2.w + w.w*a3.w + sg*as.w;
    *(float4*)(o+h) = r;
  }
}

extern "C" void kernel_launch(void* const* d_in, const int* in_sizes, int n_in,
                              void* d_out, int out_size, void* d_ws, size_t ws_size,
                              hipStream_t stream)
{
  const float* x         = (const float*)d_in[0];
  const float* router_w  = (const float*)d_in[1];
  const float* gate_w    = (const float*)d_in[2];
  const float* up_w      = (const float*)d_in[3];
  const float* down_w    = (const float*)d_in[4];
  const float* sh_gate_w = (const float*)d_in[5];
  const float* sh_up_w   = (const float*)d_in[6];
  const float* sh_down_w = (const float*)d_in[7];
  const float* eg_w      = (const float*)d_in[8];

  char* p = (char*)d_ws;
  auto alloc = [&](size_t bytes)->char*{
    char* r = p; p += (bytes + 255) & ~(size_t)255; return r;
  };
  int*   counts   = (int*)  alloc(NEXP*4);
  int*   fill     = (int*)  alloc(NEXP*4);
  int*   offsets  = (int*)  alloc((NEXP+1)*4);
  int*   topk_idx = (int*)  alloc(NSLOTS*4);
  float* topk_w   = (float*)alloc(NSLOTS*4);
  int*   slot_of  = (int*)  alloc(NSLOTS*4);
  float* gates    = (float*)alloc(TOKENS*4);
  __hip_bfloat16* xb    = (__hip_bfloat16*)alloc((size_t)TOKENS*HDIM*2);
  __hip_bfloat16* xg    = (__hip_bfloat16*)alloc((size_t)(NSLOTS+ROWPAD)*HDIM*2);
  __hip_bfloat16* act   = (__hip_bfloat16*)alloc((size_t)(NSLOTS+ROWPAD)*IDIM*2);
  __hip_bfloat16* shact = (__hip_bfloat16*)alloc((size_t)TOKENS*SIDIM*2);
  float* dslot  = (float*)alloc((size_t)NSLOTS*HDIM*4);
  float* shdown = (float*)alloc((size_t)TOKENS*HDIM*4);
  if ((size_t)(p - (char*)d_ws) > ws_size) return;

  hipMemsetAsync(counts, 0, NEXP*4, stream);
  hipMemsetAsync(fill,   0, NEXP*4, stream);

  router_kernel <<<TOKENS, 64, 0, stream>>>(x, router_w, eg_w, topk_idx, topk_w, gates, counts);
  scatter_kernel<<<TOKENS, 256, 0, stream>>>(x, topk_idx, counts, offsets, fill, slot_of, xg, xb);

  // combined gate+up: 8 XCDs x (88 shared + 165 expert) = 2024 blocks
  gateup_all<<<2024, 256, 40*1024, stream>>>(
      gate_w, up_w, xg, act,
      sh_gate_w, sh_up_w, xb, shact, offsets);

  // combined down: 8 XCDs x (32 shared + 240 expert) = 2176 blocks, 3-deep
  down_all<<<2176, 256, 36*1024, stream>>>(
      down_w, act, dslot,
      sh_down_w, shact, shdown, offsets);

  combine_kernel<<<TOKENS, 256, 0, stream>>>(dslot, shdown, slot_of, topk_w, gates, (float*)d_out);
}

// Round 12
// 595.832 us; speedup vs baseline: 1.1441x; 1.0871x over previous
//
#include <hip/hip_runtime.h>
#include <hip/hip_bf16.h>
#include <stdint.h>

#define TOKENS 512
#define HDIM   2048
#define IDIM   1408
#define SIDIM  5632
#define NEXP   60
#define TOPK   4
#define NSLOTS (TOKENS*TOPK)   /* 2048 */
#define ROWPAD 64

// counted-vmcnt barrier primitives (T3/T4): raw s_barrier, NO vmcnt(0) drain
#define VMWAIT(N) asm volatile("s_waitcnt vmcnt(" #N ")" ::: "memory")
#define SBAR()    asm volatile("s_barrier" ::: "memory")

typedef __attribute__((ext_vector_type(8))) short bf16x8;
typedef __attribute__((ext_vector_type(4))) float f32x4;

__device__ __forceinline__ short f2bf(float f){
  uint32_t u = __float_as_uint(f);
  u = (u + 0x7fffu + ((u >> 16) & 1u)) >> 16;   // RNE
  return (short)(u & 0xffffu);
}

__device__ __forceinline__ bf16x8 pack8(float4 a, float4 b){
  bf16x8 r;
  r[0]=f2bf(a.x); r[1]=f2bf(a.y); r[2]=f2bf(a.z); r[3]=f2bf(a.w);
  r[4]=f2bf(b.x); r[5]=f2bf(b.y); r[6]=f2bf(b.z); r[7]=f2bf(b.w);
  return r;
}

__device__ __forceinline__ bf16x8 as_bf16x8(float4 v){
  union { float4 f; bf16x8 b; } u; u.f = v; return u.b;
}

__device__ __forceinline__ f32x4 zero4(){
  f32x4 z; z[0]=0.f; z[1]=0.f; z[2]=0.f; z[3]=0.f; return z;
}

__device__ __forceinline__ f32x4 mfma16(bf16x8 a, bf16x8 b, f32x4 c){
  return __builtin_amdgcn_mfma_f32_16x16x32_bf16(a, b, c, 0, 0, 0);
}

// ================== K-step-32 staged tiles (rule #21 both-sides swizzle) =====
// W tile: 64 rows x 32 fp32 = 8 KB = [64][8] float4 units, rotated by row&7.
// LDS dest linear (HW); permutation rides on per-lane GLOBAL src. 2 loads/thr.
__device__ __forceinline__ void stage_w32(float4* tile, const float* __restrict__ W,
                                          int K, int k0, int tid){
  int l = tid & 63, wv = tid >> 6;
  #pragma unroll
  for (int j=0;j<2;j++){
    int u0 = j*256 + wv*64;                 // wave-uniform
    int u  = u0 + l;
    int row = u >> 3;
    int lu  = ((u & 7) - (row & 7)) & 7;
    const float* src = W + (size_t)row*K + k0 + lu*4;
    __builtin_amdgcn_global_load_lds(
        (const __attribute__((address_space(1))) void*)src,
        (__attribute__((address_space(3))) void*)(tile + u0), 16, 0, 0);
  }
}

// one B-fragment (8 bf16 = k kq*8..+8 of row r)
__device__ __forceinline__ bf16x8 read_wfrag32(const float4* tile, int r, int kq){
  int rot = r & 7;
  const float4* row = tile + (size_t)r*8;
  float4 f0 = row[(2*kq     + rot) & 7];
  float4 f1 = row[(2*kq + 1 + rot) & 7];
  return pack8(f0, f1);
}

// A tile: 64 rows x 32 bf16 = 4 KB = [64][4] float4 units, rotated by row&3.
__device__ __forceinline__ void stage_a32(float4* tile, const short* __restrict__ Arows,
                                          int K, int k0, int tid){
  int l = tid & 63, wv = tid >> 6;
  int u0 = wv*64;
  int u  = u0 + l;
  int row = u >> 2;
  int lu  = ((u & 3) - (row & 3)) & 3;
  const short* src = Arows + (size_t)row*K + k0 + lu*8;
  __builtin_amdgcn_global_load_lds(
      (const __attribute__((address_space(1))) void*)src,
      (__attribute__((address_space(3))) void*)(tile + u0), 16, 0, 0);
}

__device__ __forceinline__ void read_afrag32(const float4* tile, int c16, int kq,
                                             bf16x8* av){
  #pragma unroll
  for (int mf=0; mf<4; mf++){
    int row = c16 + 16*mf;
    av[mf] = as_bf16x8(tile[(size_t)row*4 + ((kq + row) & 3)]);
  }
}

// ---------------- router ------------------------------------------------------
__global__ __launch_bounds__(64) void router_kernel(
    const float* __restrict__ x, const float* __restrict__ rw,
    const float* __restrict__ egw, int* __restrict__ topk_idx,
    float* __restrict__ topk_w, float* __restrict__ gates,
    int* __restrict__ counts)
{
  int t = blockIdx.x;
  int lane = threadIdx.x;
  const float* xr = x + (size_t)t*HDIM;
  float xv[HDIM/64];
  #pragma unroll
  for (int i=0;i<HDIM/64;i++) xv[i] = xr[lane + 64*i];

  float mylogit = -1e30f;
  for (int e=0;e<NEXP;e++){
    const float* w = rw + (size_t)e*HDIM;
    float acc = 0.f;
    #pragma unroll
    for (int i=0;i<HDIM/64;i++) acc += xv[i]*w[lane+64*i];
    #pragma unroll
    for (int s=32;s>0;s>>=1) acc += __shfl_xor(acc, s);
    if (lane == e) mylogit = acc;
  }
  {
    float acc = 0.f;
    #pragma unroll
    for (int i=0;i<HDIM/64;i++) acc += xv[i]*egw[lane+64*i];
    #pragma unroll
    for (int s=32;s>0;s>>=1) acc += __shfl_xor(acc, s);
    if (lane == 0) gates[t] = 1.f/(1.f + __expf(-acc));
  }
  float m = mylogit;
  #pragma unroll
  for (int s=32;s>0;s>>=1) m = fmaxf(m, __shfl_xor(m, s));
  float p = (lane < NEXP) ? __expf(mylogit - m) : 0.f;
  float sum = p;
  #pragma unroll
  for (int s=32;s>0;s>>=1) sum += __shfl_xor(sum, s);
  float prob = p / sum;
  for (int k=0;k<TOPK;k++){
    float v = prob; int idx = lane;
    #pragma unroll
    for (int s=32;s>0;s>>=1){
      float ov = __shfl_xor(v, s); int oi = __shfl_xor(idx, s);
      if (ov > v || (ov == v && oi < idx)){ v = ov; idx = oi; }
    }
    if (lane == 0){
      topk_idx[t*TOPK+k] = idx;
      topk_w[t*TOPK+k]  = v;
      atomicAdd(&counts[idx], 1);
    }
    if (lane == idx) prob = -1e30f;
  }
}

// ---------------- scatter (+ folded prefix scan) ------------------------------
__global__ __launch_bounds__(256) void scatter_kernel(
    const float* __restrict__ x, const int* __restrict__ topk_idx,
    const int* __restrict__ counts, int* __restrict__ offsets,
    int* __restrict__ fill, int* __restrict__ slot_of,
    __hip_bfloat16* __restrict__ xg, __hip_bfloat16* __restrict__ xb)
{
  int t = blockIdx.x, tid = threadIdx.x;
  if (tid == 0){
    int e0 = topk_idx[t*TOPK+0], e1 = topk_idx[t*TOPK+1];
    int e2 = topk_idx[t*TOPK+2], e3 = topk_idx[t*TOPK+3];
    int o0=0,o1=0,o2=0,o3=0, acc=0;
    for (int e=0;e<NEXP;e++){
      int c = counts[e];
      if (t == 0) offsets[e] = acc;           // block 0 publishes prefix
      if (e==e0) o0=acc; if (e==e1) o1=acc;
      if (e==e2) o2=acc; if (e==e3) o3=acc;
      acc += c;
    }
    if (t == 0) offsets[NEXP] = acc;
    slot_of[t*TOPK+0] = o0 + atomicAdd(&fill[e0],1);
    slot_of[t*TOPK+1] = o1 + atomicAdd(&fill[e1],1);
    slot_of[t*TOPK+2] = o2 + atomicAdd(&fill[e2],1);
    slot_of[t*TOPK+3] = o3 + atomicAdd(&fill[e3],1);
  }
  __syncthreads();
  int4 sl = ((const int4*)slot_of)[t];
  const float4* xr = (const float4*)(x + (size_t)t*HDIM);
  float4 v0 = xr[tid*2], v1 = xr[tid*2+1];
  bf16x8 b = pack8(v0, v1);
  *(bf16x8*)((short*)xb + (size_t)t*HDIM + tid*8) = b;
  *(bf16x8*)((short*)xg + (size_t)sl.x*HDIM + tid*8) = b;
  *(bf16x8*)((short*)xg + (size_t)sl.y*HDIM + tid*8) = b;
  *(bf16x8*)((short*)xg + (size_t)sl.z*HDIM + tid*8) = b;
  *(bf16x8*)((short*)xg + (size_t)sl.w*HDIM + tid*8) = b;
}

// =============== combined gate+up GEMM ======================================
// grid = 1496 blocks (8 XCDs x 187). per-XCD: pos<22 -> shared 4-m-BATCHED
// item (s=xcd*22+pos: col-tile s%88, half s/88 covers m 256*half..+256; K-loop
// OUTER, 4 m-tiles inner -> W staged once per phase, W fabric demand 8x->2x),
// else expert q = xcd*165 + pos-22, e=q/22, bx=q%22 (R11-exact inner loop).
// LDS 64 KB (shared path: G0,G1,U0,U1 8KB + A0,A1 16KB). 2 blocks/CU.
__global__ __launch_bounds__(256, 2) void gateup_all(
    const float* __restrict__ gW_e, const float* __restrict__ uW_e,
    const __hip_bfloat16* __restrict__ A_e, __hip_bfloat16* __restrict__ out_e,
    const float* __restrict__ gW_s, const float* __restrict__ uW_s,
    const __hip_bfloat16* __restrict__ A_s, __hip_bfloat16* __restrict__ out_s,
    const int* __restrict__ offsets)
{
  extern __shared__ __align__(16) char smem[];
  int bid = blockIdx.x;
  int xcd = bid & 7, pos = bid >> 3;
  int tid  = threadIdx.x;
  int lane = tid & 63;
  int wv   = tid >> 6;
  int c16 = lane & 15, kq = lane >> 4;
  const int K = HDIM;

  if (pos < 22){
    // ---------------- shared expert: 4-m-batched, K outer ----------------
    float4* G0 = (float4*)smem;          // 512 f4
    float4* G1 = G0 + 512;
    float4* U0 = G1 + 512;
    float4* U1 = U0 + 512;
    float4* A0 = U1 + 512;               // 4 tiles x 256 f4
    float4* A1 = A0 + 1024;

    int s  = xcd*22 + pos;
    int bx = s % 88;
    int half = s / 88;                   // 0 or 1
    int wrow = bx*64 + wv*16 + c16;
    int r    = wv*16 + c16;
    const float* WgT = gW_s + (size_t)(bx*64)*K;
    const float* WuT = uW_s + (size_t)(bx*64)*K;
    const short* Ab0 = (const short*)A_s + (size_t)(half*256)*K;
    short* outp = (short*)out_s;

    f32x4 accg[4][4], accu[4][4];
    #pragma unroll
    for (int mt=0; mt<4; mt++)
      #pragma unroll
      for (int i=0;i<4;i++){ accg[mt][i] = zero4(); accu[mt][i] = zero4(); }

    stage_w32(G0, WgT, K, 0, tid);
    stage_w32(U0, WuT, K, 0, tid);
    #pragma unroll
    for (int mt=0; mt<4; mt++)
      stage_a32(A0 + mt*256, Ab0 + (size_t)mt*64*K, K, 0, tid);

    for (int k0 = 0; k0 < K; k0 += 64){
      stage_w32(G1, WgT, K, k0+32, tid);
      stage_w32(U1, WuT, K, k0+32, tid);
      #pragma unroll
      for (int mt=0; mt<4; mt++)
        stage_a32(A1 + mt*256, Ab0 + (size_t)mt*64*K, K, k0+32, tid);
      VMWAIT(8); SBAR();                  // buf0's 8 landed; buf1's 8 in flight
      {
        bf16x8 bg = read_wfrag32(G0, r, kq);
        bf16x8 bu = read_wfrag32(U0, r, kq);
        #pragma unroll
        for (int mt=0; mt<4; mt++){
          bf16x8 av[4];
          read_afrag32(A0 + mt*256, c16, kq, av);
          #pragma unroll
          for (int mf=0; mf<4; mf++){
            accg[mt][mf] = mfma16(av[mf], bg, accg[mt][mf]);
            accu[mt][mf] = mfma16(av[mf], bu, accu[mt][mf]);
          }
        }
      }
      SBAR();
      if (k0 + 64 < K){
        stage_w32(G0, WgT, K, k0+64, tid);
        stage_w32(U0, WuT, K, k0+64, tid);
        #pragma unroll
        for (int mt=0; mt<4; mt++)
          stage_a32(A0 + mt*256, Ab0 + (size_t)mt*64*K, K, k0+64, tid);
        VMWAIT(8);
      } else {
        VMWAIT(0);
      }
      SBAR();
      {
        bf16x8 bg = read_wfrag32(G1, r, kq);
        bf16x8 bu = read_wfrag32(U1, r, kq);
        #pragma unroll
        for (int mt=0; mt<4; mt++){
          bf16x8 av[4];
          read_afrag32(A1 + mt*256, c16, kq, av);
          #pragma unroll
          for (int mf=0; mf<4; mf++){
            accg[mt][mf] = mfma16(av[mf], bg, accg[mt][mf]);
            accu[mt][mf] = mfma16(av[mf], bu, accu[mt][mf]);
          }
        }
      }
      SBAR();
    }

    #pragma unroll
    for (int mt=0; mt<4; mt++){
      #pragma unroll
      for (int mf=0; mf<4; mf++){
        #pragma unroll
        for (int j=0;j<4;j++){
          int row = half*256 + mt*64 + mf*16 + kq*4 + j;
          float g = accg[mt][mf][j], u = accu[mt][mf][j];
          float sv = g * u / (1.f + __expf(-g));
          outp[(size_t)row*SIDIM + wrow] = f2bf(sv);
        }
      }
    }
    return;
  }

  // ---------------- routed experts: R11-exact inner loop ----------------
  {
    float4* G0 = (float4*)smem;
    float4* G1 = G0 + 512;
    float4* U0 = G1 + 512;
    float4* U1 = U0 + 512;
    float4* A0 = U1 + 512;
    float4* A1 = A0 + 256;

    int q = xcd*165 + (pos - 22);
    int e = q/22, bx = q - e*22;
    size_t wo = (size_t)e * IDIM * HDIM;
    const float* Wg = gW_e + wo;
    const float* Wu = uW_e + wo;
    const short* Abase = (const short*)A_e;
    short* outp = (short*)out_e;
    int m_start = offsets[e], m_end = offsets[e+1];
    if (m_start >= m_end) return;

    int wrow = bx*64 + wv*16 + c16;
    int r    = wv*16 + c16;
    const float* WgT = Wg + (size_t)(bx*64)*K;
    const float* WuT = Wu + (size_t)(bx*64)*K;

    for (int m0 = m_start; m0 < m_end; m0 += 64){
      int mrem = m_end - m0;
      const short* Ar = Abase + (size_t)m0*K;
      f32x4 accg[4], accu[4];
      #pragma unroll
      for (int i=0;i<4;i++){ accg[i] = zero4(); accu[i] = zero4(); }

      stage_w32(G0, WgT, K, 0, tid);
      stage_w32(U0, WuT, K, 0, tid);
      stage_a32(A0, Ar,  K, 0, tid);

      for (int k0 = 0; k0 < K; k0 += 64){
        stage_w32(G1, WgT, K, k0+32, tid);
        stage_w32(U1, WuT, K, k0+32, tid);
        stage_a32(A1, Ar,  K, k0+32, tid);
        VMWAIT(5); SBAR();
        {
          bf16x8 av[4];
          read_afrag32(A0, c16, kq, av);
          bf16x8 bg = read_wfrag32(G0, r, kq);
          bf16x8 bu = read_wfrag32(U0, r, kq);
          #pragma unroll
          for (int mf=0; mf<4; mf++){
            accg[mf] = mfma16(av[mf], bg, accg[mf]);
            accu[mf] = mfma16(av[mf], bu, accu[mf]);
          }
        }
        SBAR();
        if (k0 + 64 < K){
          stage_w32(G0, WgT, K, k0+64, tid);
          stage_w32(U0, WuT, K, k0+64, tid);
          stage_a32(A0, Ar,  K, k0+64, tid);
          VMWAIT(5);
        } else {
          VMWAIT(0);
        }
        SBAR();
        {
          bf16x8 av[4];
          read_afrag32(A1, c16, kq, av);
          bf16x8 bg = read_wfrag32(G1, r, kq);
          bf16x8 bu = read_wfrag32(U1, r, kq);
          #pragma unroll
          for (int mf=0; mf<4; mf++){
            accg[mf] = mfma16(av[mf], bg, accg[mf]);
            accu[mf] = mfma16(av[mf], bu, accu[mf]);
          }
        }
        SBAR();
      }

      #pragma unroll
      for (int mf=0; mf<4; mf++){
        #pragma unroll
        for (int j=0;j<4;j++){
          int mrow = mf*16 + kq*4 + j;
          if (mrow < mrem){
            float g = accg[mf][j], u = accu[mf][j];
            float sv = g * u / (1.f + __expf(-g));
            outp[(size_t)(m0+mrow)*IDIM + wrow] = f2bf(sv);
          }
        }
      }
    }
  }
}

// =============== combined down GEMM (R11-exact: 3-deep pipeline) =============
// grid = 2176 blocks (8 x 272). per-XCD: pos<32 -> shared (m-tile=xcd,
// K=SIDIM, heavy: first), else expert q = xcd*240+pos-32, e=q/32.
// LDS 36 KB: W slots x3 (8 KB) + A slots x3 (4 KB) -> 4 blocks/CU.
__global__ __launch_bounds__(256, 4) void down_all(
    const float* __restrict__ W_e, const __hip_bfloat16* __restrict__ A_e,
    float* __restrict__ out_e,
    const float* __restrict__ W_s, const __hip_bfloat16* __restrict__ A_s,
    float* __restrict__ out_s,
    const int* __restrict__ offsets)
{
  extern __shared__ __align__(16) char smem[];
  float4* Wb = (float4*)smem;          // 3 x 512 float4
  float4* Ab = Wb + 3*512;             // 3 x 256 float4

  int bid = blockIdx.x;
  int xcd = bid & 7, pos = bid >> 3;
  const float* W; const short* Abase; float* outp;
  int K, bx, m_start, m_end;
  if (pos < 32){                       // shared expert (long blocks first)
    bx = pos;
    W = W_s; Abase = (const short*)A_s; outp = out_s; K = SIDIM;
    m_start = xcd*64; m_end = m_start + 64;
  } else {
    int q = xcd*240 + (pos - 32);
    int e = q >> 5; bx = q & 31;
    W = W_e + (size_t)e * HDIM * IDIM;
    Abase = (const short*)A_e; outp = out_e; K = IDIM;
    m_start = offsets[e]; m_end = offsets[e+1];
  }
  if (m_start >= m_end) return;

  int tid  = threadIdx.x;
  int lane = tid & 63;
  int wv   = tid >> 6;
  int c16 = lane & 15, kq = lane >> 4;
  int wrow = bx*64 + wv*16 + c16;
  int r    = wv*16 + c16;
  const float* WT = W + (size_t)(bx*64)*K;
  int np = K >> 5;                     // phases of 32 k-floats

  for (int m0 = m_start; m0 < m_end; m0 += 64){
    int mrem = m_end - m0;
    const short* Ar = Abase + (size_t)m0*K;
    f32x4 acc[4];
    #pragma unroll
    for (int i=0;i<4;i++) acc[i] = zero4();

    // prologue: tiles 0 and 1 in flight (6 loads/thread)
    stage_w32(Wb,       WT, K, 0,  tid);
    stage_a32(Ab,       Ar, K, 0,  tid);
    stage_w32(Wb + 512, WT, K, 32, tid);
    stage_a32(Ab + 256, Ar, K, 32, tid);

    int cs = 0, ss = 2;                // compute slot (p%3), stage slot ((p+2)%3)
    for (int p = 0; p < np; ++p){
      if (p + 2 < np){
        stage_w32(Wb + ss*512, WT, K, (p+2) << 5, tid);
        stage_a32(Ab + ss*256, Ar, K, (p+2) << 5, tid);
        VMWAIT(6);                     // tile p landed; p+1, p+2 in flight
      } else if (p + 1 < np){
        VMWAIT(3);                     // tile p landed; p+1 in flight
      } else {
        VMWAIT(0);                     // last tile
      }
      SBAR();
      {
        bf16x8 av[4];
        read_afrag32(Ab + cs*256, c16, kq, av);
        bf16x8 b = read_wfrag32(Wb + cs*512, r, kq);
        #pragma unroll
        for (int mf=0; mf<4; mf++)
          acc[mf] = mfma16(av[mf], b, acc[mf]);
      }
      SBAR();                          // all reads of slot cs done before restage
      cs = (cs == 2) ? 0 : cs + 1;
      ss = (ss == 2) ? 0 : ss + 1;
    }

    #pragma unroll
    for (int mf=0; mf<4; mf++){
      #pragma unroll
      for (int j=0;j<4;j++){
        int mrow = mf*16 + kq*4 + j;
        if (mrow < mrem)
          outp[(size_t)(m0+mrow)*HDIM + wrow] = acc[mf][j];
      }
    }
  }
}

// ---------------- final combine ----------------------------------------------
__global__ __launch_bounds__(256) void combine_kernel(
    const float* __restrict__ dslot, const float* __restrict__ shdown,
    const int* __restrict__ slot_of, const float* __restrict__ topw,
    const float* __restrict__ gates, float* __restrict__ out)
{
  int t = blockIdx.x, tid = threadIdx.x;
  int4  sl = ((const int4*)slot_of)[t];
  float4 w = ((const float4*)topw)[t];
  float sg = gates[t];
  const float* r0 = dslot + (size_t)sl.x*HDIM;
  const float* r1 = dslot + (size_t)sl.y*HDIM;
  const float* r2 = dslot + (size_t)sl.z*HDIM;
  const float* r3 = dslot + (size_t)sl.w*HDIM;
  const float* rs = shdown + (size_t)t*HDIM;
  float* o = out + (size_t)t*HDIM;
  #pragma unroll
  for (int it=0; it<HDIM/(256*4); ++it){
    int h = (tid + it*256) * 4;
    float4 a0 = *(const float4*)(r0+h);
    float4 a1 = *(const float4*)(r1+h);
    float4 a2 = *(const float4*)(r2+h);
    float4 a3 = *(const float4*)(r3+h);
    float4 as = *(const float4*)(rs+h);
    float4 r;
    r.x = w.x*a0.x + w.y*a1.x + w.z*a2.x + w.w*a3.x + sg*as.x;
    r.y = w.x*a0.y + w.y*a1.y + w.z*a2.y + w.w*a3.y + sg*as.y;
    r.z = w.x*a0.z + w.y*a1.z + w.z*a2.z + w.w*a3.z + sg*as.z;
    r.w = w.x*a0.w + w.y*a1.w + w.z*a2.w + w.w*a3.w + sg*as.w;
    *(float4*)(o+h) = r;
  }
}

extern "C" void kernel_launch(void* const* d_in, const int* in_sizes, int n_in,
                              void* d_out, int out_size, void* d_ws, size_t ws_size,
                              hipStream_t stream)
{
  const float* x         = (const float*)d_in[0];
  const float* router_w  = (const float*)d_in[1];
  const float* gate_w    = (const float*)d_in[2];
  const float* up_w      = (const float*)d_in[3];
  const float* down_w    = (const float*)d_in[4];
  const float* sh_gate_w = (const float*)d_in[5];
  const float* sh_up_w   = (const float*)d_in[6];
  const float* sh_down_w = (const float*)d_in[7];
  const float* eg_w      = (const float*)d_in[8];

  char* p = (char*)d_ws;
  auto alloc = [&](size_t bytes)->char*{
    char* r = p; p += (bytes + 255) & ~(size_t)255; return r;
  };
  int*   counts   = (int*)  alloc(NEXP*4);
  int*   fill     = (int*)  alloc(NEXP*4);
  int*   offsets  = (int*)  alloc((NEXP+1)*4);
  int*   topk_idx = (int*)  alloc(NSLOTS*4);
  float* topk_w   = (float*)alloc(NSLOTS*4);
  int*   slot_of  = (int*)  alloc(NSLOTS*4);
  float* gates    = (float*)alloc(TOKENS*4);
  __hip_bfloat16* xb    = (__hip_bfloat16*)alloc((size_t)TOKENS*HDIM*2);
  __hip_bfloat16* xg    = (__hip_bfloat16*)alloc((size_t)(NSLOTS+ROWPAD)*HDIM*2);
  __hip_bfloat16* act   = (__hip_bfloat16*)alloc((size_t)(NSLOTS+ROWPAD)*IDIM*2);
  __hip_bfloat16* shact = (__hip_bfloat16*)alloc((size_t)TOKENS*SIDIM*2);
  float* dslot  = (float*)alloc((size_t)NSLOTS*HDIM*4);
  float* shdown = (float*)alloc((size_t)TOKENS*HDIM*4);
  if ((size_t)(p - (char*)d_ws) > ws_size) return;

  hipMemsetAsync(counts, 0, NEXP*4, stream);
  hipMemsetAsync(fill,   0, NEXP*4, stream);

  router_kernel <<<TOKENS, 64, 0, stream>>>(x, router_w, eg_w, topk_idx, topk_w, gates, counts);
  scatter_kernel<<<TOKENS, 256, 0, stream>>>(x, topk_idx, counts, offsets, fill, slot_of, xg, xb);

  // combined gate+up: 8 XCDs x (22 shared-4m-batched + 165 expert) = 1496 blocks
  gateup_all<<<1496, 256, 64*1024, stream>>>(
      gate_w, up_w, xg, act,
      sh_gate_w, sh_up_w, xb, shact, offsets);

  // combined down: 8 XCDs x (32 shared + 240 expert) = 2176 blocks, 3-deep
  down_all<<<2176, 256, 36*1024, stream>>>(
      down_w, act, dslot,
      sh_down_w, shact, shdown, offsets);

  combine_kernel<<<TOKENS, 256, 0, stream>>>(dslot, shdown, slot_of, topk_w, gates, (float*)d_out);
}

// Round 13
// 591.141 us; speedup vs baseline: 1.1532x; 1.0079x over previous
//
#include <hip/hip_runtime.h>
#include <hip/hip_bf16.h>
#include <stdint.h>

#define TOKENS 512
#define HDIM   2048
#define IDIM   1408
#define SIDIM  5632
#define NEXP   60
#define TOPK   4
#define NSLOTS (TOKENS*TOPK)   /* 2048 */
#define ROWPAD 64

// counted-vmcnt barrier primitives (T3/T4): raw s_barrier, NO vmcnt(0) drain
#define VMWAIT(N) asm volatile("s_waitcnt vmcnt(" #N ")" ::: "memory")
#define SBAR()    asm volatile("s_barrier" ::: "memory")

typedef __attribute__((ext_vector_type(8))) short bf16x8;
typedef __attribute__((ext_vector_type(4))) float f32x4;

__device__ __forceinline__ short f2bf(float f){
  uint32_t u = __float_as_uint(f);
  u = (u + 0x7fffu + ((u >> 16) & 1u)) >> 16;   // RNE
  return (short)(u & 0xffffu);
}

__device__ __forceinline__ bf16x8 pack8(float4 a, float4 b){
  bf16x8 r;
  r[0]=f2bf(a.x); r[1]=f2bf(a.y); r[2]=f2bf(a.z); r[3]=f2bf(a.w);
  r[4]=f2bf(b.x); r[5]=f2bf(b.y); r[6]=f2bf(b.z); r[7]=f2bf(b.w);
  return r;
}

__device__ __forceinline__ bf16x8 as_bf16x8(float4 v){
  union { float4 f; bf16x8 b; } u; u.f = v; return u.b;
}

__device__ __forceinline__ f32x4 zero4(){
  f32x4 z; z[0]=0.f; z[1]=0.f; z[2]=0.f; z[3]=0.f; return z;
}

__device__ __forceinline__ f32x4 mfma16(bf16x8 a, bf16x8 b, f32x4 c){
  return __builtin_amdgcn_mfma_f32_16x16x32_bf16(a, b, c, 0, 0, 0);
}

// ================== K-step-32 staged tiles (rule #21 both-sides swizzle) =====
// W tile: 64 rows x 32 fp32 = 8 KB = [64][8] float4 units, rotated by row&7.
// LDS dest linear (HW); permutation rides on per-lane GLOBAL src. 2 loads/thr.
__device__ __forceinline__ void stage_w32(float4* tile, const float* __restrict__ W,
                                          int K, int k0, int tid){
  int l = tid & 63, wv = tid >> 6;
  #pragma unroll
  for (int j=0;j<2;j++){
    int u0 = j*256 + wv*64;                 // wave-uniform
    int u  = u0 + l;
    int row = u >> 3;
    int lu  = ((u & 7) - (row & 7)) & 7;
    const float* src = W + (size_t)row*K + k0 + lu*4;
    __builtin_amdgcn_global_load_lds(
        (const __attribute__((address_space(1))) void*)src,
        (__attribute__((address_space(3))) void*)(tile + u0), 16, 0, 0);
  }
}

// one B-fragment (8 bf16 = k kq*8..+8 of row r)
__device__ __forceinline__ bf16x8 read_wfrag32(const float4* tile, int r, int kq){
  int rot = r & 7;
  const float4* row = tile + (size_t)r*8;
  float4 f0 = row[(2*kq     + rot) & 7];
  float4 f1 = row[(2*kq + 1 + rot) & 7];
  return pack8(f0, f1);
}

// A tile: 64 rows x 32 bf16 = 4 KB = [64][4] float4 units, rotated by row&3.
__device__ __forceinline__ void stage_a32(float4* tile, const short* __restrict__ Arows,
                                          int K, int k0, int tid){
  int l = tid & 63, wv = tid >> 6;
  int u0 = wv*64;
  int u  = u0 + l;
  int row = u >> 2;
  int lu  = ((u & 3) - (row & 3)) & 3;
  const short* src = Arows + (size_t)row*K + k0 + lu*8;
  __builtin_amdgcn_global_load_lds(
      (const __attribute__((address_space(1))) void*)src,
      (__attribute__((address_space(3))) void*)(tile + u0), 16, 0, 0);
}

__device__ __forceinline__ void read_afrag32(const float4* tile, int c16, int kq,
                                             bf16x8* av){
  #pragma unroll
  for (int mf=0; mf<4; mf++){
    int row = c16 + 16*mf;
    av[mf] = as_bf16x8(tile[(size_t)row*4 + ((kq + row) & 3)]);
  }
}

// ---------------- router ------------------------------------------------------
__global__ __launch_bounds__(64) void router_kernel(
    const float* __restrict__ x, const float* __restrict__ rw,
    const float* __restrict__ egw, int* __restrict__ topk_idx,
    float* __restrict__ topk_w, float* __restrict__ gates,
    int* __restrict__ counts)
{
  int t = blockIdx.x;
  int lane = threadIdx.x;
  const float* xr = x + (size_t)t*HDIM;
  float xv[HDIM/64];
  #pragma unroll
  for (int i=0;i<HDIM/64;i++) xv[i] = xr[lane + 64*i];

  float mylogit = -1e30f;
  for (int e=0;e<NEXP;e++){
    const float* w = rw + (size_t)e*HDIM;
    float acc = 0.f;
    #pragma unroll
    for (int i=0;i<HDIM/64;i++) acc += xv[i]*w[lane+64*i];
    #pragma unroll
    for (int s=32;s>0;s>>=1) acc += __shfl_xor(acc, s);
    if (lane == e) mylogit = acc;
  }
  {
    float acc = 0.f;
    #pragma unroll
    for (int i=0;i<HDIM/64;i++) acc += xv[i]*egw[lane+64*i];
    #pragma unroll
    for (int s=32;s>0;s>>=1) acc += __shfl_xor(acc, s);
    if (lane == 0) gates[t] = 1.f/(1.f + __expf(-acc));
  }
  float m = mylogit;
  #pragma unroll
  for (int s=32;s>0;s>>=1) m = fmaxf(m, __shfl_xor(m, s));
  float p = (lane < NEXP) ? __expf(mylogit - m) : 0.f;
  float sum = p;
  #pragma unroll
  for (int s=32;s>0;s>>=1) sum += __shfl_xor(sum, s);
  float prob = p / sum;
  for (int k=0;k<TOPK;k++){
    float v = prob; int idx = lane;
    #pragma unroll
    for (int s=32;s>0;s>>=1){
      float ov = __shfl_xor(v, s); int oi = __shfl_xor(idx, s);
      if (ov > v || (ov == v && oi < idx)){ v = ov; idx = oi; }
    }
    if (lane == 0){
      topk_idx[t*TOPK+k] = idx;
      topk_w[t*TOPK+k]  = v;
      atomicAdd(&counts[idx], 1);
    }
    if (lane == idx) prob = -1e30f;
  }
}

// ---------------- scatter (+ folded prefix scan) ------------------------------
__global__ __launch_bounds__(256) void scatter_kernel(
    const float* __restrict__ x, const int* __restrict__ topk_idx,
    const int* __restrict__ counts, int* __restrict__ offsets,
    int* __restrict__ fill, int* __restrict__ slot_of,
    __hip_bfloat16* __restrict__ xg, __hip_bfloat16* __restrict__ xb)
{
  int t = blockIdx.x, tid = threadIdx.x;
  if (tid == 0){
    int e0 = topk_idx[t*TOPK+0], e1 = topk_idx[t*TOPK+1];
    int e2 = topk_idx[t*TOPK+2], e3 = topk_idx[t*TOPK+3];
    int o0=0,o1=0,o2=0,o3=0, acc=0;
    for (int e=0;e<NEXP;e++){
      int c = counts[e];
      if (t == 0) offsets[e] = acc;           // block 0 publishes prefix
      if (e==e0) o0=acc; if (e==e1) o1=acc;
      if (e==e2) o2=acc; if (e==e3) o3=acc;
      acc += c;
    }
    if (t == 0) offsets[NEXP] = acc;
    slot_of[t*TOPK+0] = o0 + atomicAdd(&fill[e0],1);
    slot_of[t*TOPK+1] = o1 + atomicAdd(&fill[e1],1);
    slot_of[t*TOPK+2] = o2 + atomicAdd(&fill[e2],1);
    slot_of[t*TOPK+3] = o3 + atomicAdd(&fill[e3],1);
  }
  __syncthreads();
  int4 sl = ((const int4*)slot_of)[t];
  const float4* xr = (const float4*)(x + (size_t)t*HDIM);
  float4 v0 = xr[tid*2], v1 = xr[tid*2+1];
  bf16x8 b = pack8(v0, v1);
  *(bf16x8*)((short*)xb + (size_t)t*HDIM + tid*8) = b;
  *(bf16x8*)((short*)xg + (size_t)sl.x*HDIM + tid*8) = b;
  *(bf16x8*)((short*)xg + (size_t)sl.y*HDIM + tid*8) = b;
  *(bf16x8*)((short*)xg + (size_t)sl.z*HDIM + tid*8) = b;
  *(bf16x8*)((short*)xg + (size_t)sl.w*HDIM + tid*8) = b;
}

// =============== combined gate+up GEMM ======================================
// grid = 1496 blocks (8 XCDs x 187). per-XCD: pos<22 -> shared 4-m-BATCHED
// item. R13 remap: col-tile bx = xcd*11 + pos/2, half = pos&1 -> BOTH halves
// of a col-tile on the SAME XCD, adjacent in dispatch => second half's W is
// L2-served (shared-W fabric 2x -> 1x). Expert: q = xcd*165 + pos-22,
// e=q/22, bx=q%22 (R11-exact inner loop).
// LDS 64 KB (shared path: G0,G1,U0,U1 8KB + A0,A1 16KB). 2 blocks/CU.
__global__ __launch_bounds__(256, 2) void gateup_all(
    const float* __restrict__ gW_e, const float* __restrict__ uW_e,
    const __hip_bfloat16* __restrict__ A_e, __hip_bfloat16* __restrict__ out_e,
    const float* __restrict__ gW_s, const float* __restrict__ uW_s,
    const __hip_bfloat16* __restrict__ A_s, __hip_bfloat16* __restrict__ out_s,
    const int* __restrict__ offsets)
{
  extern __shared__ __align__(16) char smem[];
  int bid = blockIdx.x;
  int xcd = bid & 7, pos = bid >> 3;
  int tid  = threadIdx.x;
  int lane = tid & 63;
  int wv   = tid >> 6;
  int c16 = lane & 15, kq = lane >> 4;
  const int K = HDIM;

  if (pos < 22){
    // ---------------- shared expert: 4-m-batched, K outer ----------------
    float4* G0 = (float4*)smem;          // 512 f4
    float4* G1 = G0 + 512;
    float4* U0 = G1 + 512;
    float4* U1 = U0 + 512;
    float4* A0 = U1 + 512;               // 4 tiles x 256 f4
    float4* A1 = A0 + 1024;

    int bx   = xcd*11 + (pos >> 1);      // 11 col-tiles per XCD
    int half = pos & 1;                  // both halves same XCD, adjacent
    int wrow = bx*64 + wv*16 + c16;
    int r    = wv*16 + c16;
    const float* WgT = gW_s + (size_t)(bx*64)*K;
    const float* WuT = uW_s + (size_t)(bx*64)*K;
    const short* Ab0 = (const short*)A_s + (size_t)(half*256)*K;
    short* outp = (short*)out_s;

    f32x4 accg[4][4], accu[4][4];
    #pragma unroll
    for (int mt=0; mt<4; mt++)
      #pragma unroll
      for (int i=0;i<4;i++){ accg[mt][i] = zero4(); accu[mt][i] = zero4(); }

    stage_w32(G0, WgT, K, 0, tid);
    stage_w32(U0, WuT, K, 0, tid);
    #pragma unroll
    for (int mt=0; mt<4; mt++)
      stage_a32(A0 + mt*256, Ab0 + (size_t)mt*64*K, K, 0, tid);

    for (int k0 = 0; k0 < K; k0 += 64){
      stage_w32(G1, WgT, K, k0+32, tid);
      stage_w32(U1, WuT, K, k0+32, tid);
      #pragma unroll
      for (int mt=0; mt<4; mt++)
        stage_a32(A1 + mt*256, Ab0 + (size_t)mt*64*K, K, k0+32, tid);
      VMWAIT(8); SBAR();                  // buf0's 8 landed; buf1's 8 in flight
      {
        bf16x8 bg = read_wfrag32(G0, r, kq);
        bf16x8 bu = read_wfrag32(U0, r, kq);
        #pragma unroll
        for (int mt=0; mt<4; mt++){
          bf16x8 av[4];
          read_afrag32(A0 + mt*256, c16, kq, av);
          #pragma unroll
          for (int mf=0; mf<4; mf++){
            accg[mt][mf] = mfma16(av[mf], bg, accg[mt][mf]);
            accu[mt][mf] = mfma16(av[mf], bu, accu[mt][mf]);
          }
        }
      }
      SBAR();
      if (k0 + 64 < K){
        stage_w32(G0, WgT, K, k0+64, tid);
        stage_w32(U0, WuT, K, k0+64, tid);
        #pragma unroll
        for (int mt=0; mt<4; mt++)
          stage_a32(A0 + mt*256, Ab0 + (size_t)mt*64*K, K, k0+64, tid);
        VMWAIT(8);
      } else {
        VMWAIT(0);
      }
      SBAR();
      {
        bf16x8 bg = read_wfrag32(G1, r, kq);
        bf16x8 bu = read_wfrag32(U1, r, kq);
        #pragma unroll
        for (int mt=0; mt<4; mt++){
          bf16x8 av[4];
          read_afrag32(A1 + mt*256, c16, kq, av);
          #pragma unroll
          for (int mf=0; mf<4; mf++){
            accg[mt][mf] = mfma16(av[mf], bg, accg[mt][mf]);
            accu[mt][mf] = mfma16(av[mf], bu, accu[mt][mf]);
          }
        }
      }
      SBAR();
    }

    #pragma unroll
    for (int mt=0; mt<4; mt++){
      #pragma unroll
      for (int mf=0; mf<4; mf++){
        #pragma unroll
        for (int j=0;j<4;j++){
          int row = half*256 + mt*64 + mf*16 + kq*4 + j;
          float g = accg[mt][mf][j], u = accu[mt][mf][j];
          float sv = g * u / (1.f + __expf(-g));
          outp[(size_t)row*SIDIM + wrow] = f2bf(sv);
        }
      }
    }
    return;
  }

  // ---------------- routed experts: R11-exact inner loop ----------------
  {
    float4* G0 = (float4*)smem;
    float4* G1 = G0 + 512;
    float4* U0 = G1 + 512;
    float4* U1 = U0 + 512;
    float4* A0 = U1 + 512;
    float4* A1 = A0 + 256;

    int q = xcd*165 + (pos - 22);
    int e = q/22, bx = q - e*22;
    size_t wo = (size_t)e * IDIM * HDIM;
    const float* Wg = gW_e + wo;
    const float* Wu = uW_e + wo;
    const short* Abase = (const short*)A_e;
    short* outp = (short*)out_e;
    int m_start = offsets[e], m_end = offsets[e+1];
    if (m_start >= m_end) return;

    int wrow = bx*64 + wv*16 + c16;
    int r    = wv*16 + c16;
    const float* WgT = Wg + (size_t)(bx*64)*K;
    const float* WuT = Wu + (size_t)(bx*64)*K;

    for (int m0 = m_start; m0 < m_end; m0 += 64){
      int mrem = m_end - m0;
      const short* Ar = Abase + (size_t)m0*K;
      f32x4 accg[4], accu[4];
      #pragma unroll
      for (int i=0;i<4;i++){ accg[i] = zero4(); accu[i] = zero4(); }

      stage_w32(G0, WgT, K, 0, tid);
      stage_w32(U0, WuT, K, 0, tid);
      stage_a32(A0, Ar,  K, 0, tid);

      for (int k0 = 0; k0 < K; k0 += 64){
        stage_w32(G1, WgT, K, k0+32, tid);
        stage_w32(U1, WuT, K, k0+32, tid);
        stage_a32(A1, Ar,  K, k0+32, tid);
        VMWAIT(5); SBAR();
        {
          bf16x8 av[4];
          read_afrag32(A0, c16, kq, av);
          bf16x8 bg = read_wfrag32(G0, r, kq);
          bf16x8 bu = read_wfrag32(U0, r, kq);
          #pragma unroll
          for (int mf=0; mf<4; mf++){
            accg[mf] = mfma16(av[mf], bg, accg[mf]);
            accu[mf] = mfma16(av[mf], bu, accu[mf]);
          }
        }
        SBAR();
        if (k0 + 64 < K){
          stage_w32(G0, WgT, K, k0+64, tid);
          stage_w32(U0, WuT, K, k0+64, tid);
          stage_a32(A0, Ar,  K, k0+64, tid);
          VMWAIT(5);
        } else {
          VMWAIT(0);
        }
        SBAR();
        {
          bf16x8 av[4];
          read_afrag32(A1, c16, kq, av);
          bf16x8 bg = read_wfrag32(G1, r, kq);
          bf16x8 bu = read_wfrag32(U1, r, kq);
          #pragma unroll
          for (int mf=0; mf<4; mf++){
            accg[mf] = mfma16(av[mf], bg, accg[mf]);
            accu[mf] = mfma16(av[mf], bu, accu[mf]);
          }
        }
        SBAR();
      }

      #pragma unroll
      for (int mf=0; mf<4; mf++){
        #pragma unroll
        for (int j=0;j<4;j++){
          int mrow = mf*16 + kq*4 + j;
          if (mrow < mrem){
            float g = accg[mf][j], u = accu[mf][j];
            float sv = g * u / (1.f + __expf(-g));
            outp[(size_t)(m0+mrow)*IDIM + wrow] = f2bf(sv);
          }
        }
      }
    }
  }
}

// =============== combined down GEMM (R11 3-deep pipeline + R13 remap) ========
// grid = 2176 blocks (8 x 272). per-XCD: pos<32 -> shared; R13 remap:
// col-tile bx = xcd*4 + pos/8, m-tile = pos&7 -> all 8 m-repeats of a W
// col-tile on the SAME XCD, adjacent => 7/8 W re-stages L2-served (shared-W
// fabric 8x -> 1x; A moves to 4x-L2-shared). Expert: q = xcd*240+pos-32.
// LDS 36 KB: W slots x3 (8 KB) + A slots x3 (4 KB) -> 4 blocks/CU.
__global__ __launch_bounds__(256, 4) void down_all(
    const float* __restrict__ W_e, const __hip_bfloat16* __restrict__ A_e,
    float* __restrict__ out_e,
    const float* __restrict__ W_s, const __hip_bfloat16* __restrict__ A_s,
    float* __restrict__ out_s,
    const int* __restrict__ offsets)
{
  extern __shared__ __align__(16) char smem[];
  float4* Wb = (float4*)smem;          // 3 x 512 float4
  float4* Ab = Wb + 3*512;             // 3 x 256 float4

  int bid = blockIdx.x;
  int xcd = bid & 7, pos = bid >> 3;
  const float* W; const short* Abase; float* outp;
  int K, bx, m_start, m_end;
  if (pos < 32){                       // shared expert (long blocks first)
    bx = xcd*4 + (pos >> 3);           // 4 col-tiles per XCD
    int mt = pos & 7;                  // 8 m-tiles, same XCD, adjacent
    W = W_s; Abase = (const short*)A_s; outp = out_s; K = SIDIM;
    m_start = mt*64; m_end = m_start + 64;
  } else {
    int q = xcd*240 + (pos - 32);
    int e = q >> 5; bx = q & 31;
    W = W_e + (size_t)e * HDIM * IDIM;
    Abase = (const short*)A_e; outp = out_e; K = IDIM;
    m_start = offsets[e]; m_end = offsets[e+1];
  }
  if (m_start >= m_end) return;

  int tid  = threadIdx.x;
  int lane = tid & 63;
  int wv   = tid >> 6;
  int c16 = lane & 15, kq = lane >> 4;
  int wrow = bx*64 + wv*16 + c16;
  int r    = wv*16 + c16;
  const float* WT = W + (size_t)(bx*64)*K;
  int np = K >> 5;                     // phases of 32 k-floats

  for (int m0 = m_start; m0 < m_end; m0 += 64){
    int mrem = m_end - m0;
    const short* Ar = Abase + (size_t)m0*K;
    f32x4 acc[4];
    #pragma unroll
    for (int i=0;i<4;i++) acc[i] = zero4();

    // prologue: tiles 0 and 1 in flight (6 loads/thread)
    stage_w32(Wb,       WT, K, 0,  tid);
    stage_a32(Ab,       Ar, K, 0,  tid);
    stage_w32(Wb + 512, WT, K, 32, tid);
    stage_a32(Ab + 256, Ar, K, 32, tid);

    int cs = 0, ss = 2;                // compute slot (p%3), stage slot ((p+2)%3)
    for (int p = 0; p < np; ++p){
      if (p + 2 < np){
        stage_w32(Wb + ss*512, WT, K, (p+2) << 5, tid);
        stage_a32(Ab + ss*256, Ar, K, (p+2) << 5, tid);
        VMWAIT(6);                     // tile p landed; p+1, p+2 in flight
      } else if (p + 1 < np){
        VMWAIT(3);                     // tile p landed; p+1 in flight
      } else {
        VMWAIT(0);                     // last tile
      }
      SBAR();
      {
        bf16x8 av[4];
        read_afrag32(Ab + cs*256, c16, kq, av);
        bf16x8 b = read_wfrag32(Wb + cs*512, r, kq);
        #pragma unroll
        for (int mf=0; mf<4; mf++)
          acc[mf] = mfma16(av[mf], b, acc[mf]);
      }
      SBAR();                          // all reads of slot cs done before restage
      cs = (cs == 2) ? 0 : cs + 1;
      ss = (ss == 2) ? 0 : ss + 1;
    }

    #pragma unroll
    for (int mf=0; mf<4; mf++){
      #pragma unroll
      for (int j=0;j<4;j++){
        int mrow = mf*16 + kq*4 + j;
        if (mrow < mrem)
          outp[(size_t)(m0+mrow)*HDIM + wrow] = acc[mf][j];
      }
    }
  }
}

// ---------------- final combine ----------------------------------------------
__global__ __launch_bounds__(256) void combine_kernel(
    const float* __restrict__ dslot, const float* __restrict__ shdown,
    const int* __restrict__ slot_of, const float* __restrict__ topw,
    const float* __restrict__ gates, float* __restrict__ out)
{
  int t = blockIdx.x, tid = threadIdx.x;
  int4  sl = ((const int4*)slot_of)[t];
  float4 w = ((const float4*)topw)[t];
  float sg = gates[t];
  const float* r0 = dslot + (size_t)sl.x*HDIM;
  const float* r1 = dslot + (size_t)sl.y*HDIM;
  const float* r2 = dslot + (size_t)sl.z*HDIM;
  const float* r3 = dslot + (size_t)sl.w*HDIM;
  const float* rs = shdown + (size_t)t*HDIM;
  float* o = out + (size_t)t*HDIM;
  #pragma unroll
  for (int it=0; it<HDIM/(256*4); ++it){
    int h = (tid + it*256) * 4;
    float4 a0 = *(const float4*)(r0+h);
    float4 a1 = *(const float4*)(r1+h);
    float4 a2 = *(const float4*)(r2+h);
    float4 a3 = *(const float4*)(r3+h);
    float4 as = *(const float4*)(rs+h);
    float4 r;
    r.x = w.x*a0.x + w.y*a1.x + w.z*a2.x + w.w*a3.x + sg*as.x;
    r.y = w.x*a0.y + w.y*a1.y + w.z*a2.y + w.w*a3.y + sg*as.y;
    r.z = w.x*a0.z + w.y*a1.z + w.z*a2.z + w.w*a3.z + sg*as.z;
    r.w = w.x*a0.w + w.y*a1.w + w.z*a2.w + w.w*a3.w + sg*as.w;
    *(float4*)(o+h) = r;
  }
}

extern "C" void kernel_launch(void* const* d_in, const int* in_sizes, int n_in,
                              void* d_out, int out_size, void* d_ws, size_t ws_size,
                              hipStream_t stream)
{
  const float* x         = (const float*)d_in[0];
  const float* router_w  = (const float*)d_in[1];
  const float* gate_w    = (const float*)d_in[2];
  const float* up_w      = (const float*)d_in[3];
  const float* down_w    = (const float*)d_in[4];
  const float* sh_gate_w = (const float*)d_in[5];
  const float* sh_up_w   = (const float*)d_in[6];
  const float* sh_down_w = (const float*)d_in[7];
  const float* eg_w      = (const float*)d_in[8];

  char* p = (char*)d_ws;
  auto alloc = [&](size_t bytes)->char*{
    char* r = p; p += (bytes + 255) & ~(size_t)255; return r;
  };
  int*   counts   = (int*)  alloc(NEXP*4);
  int*   fill     = (int*)  alloc(NEXP*4);
  int*   offsets  = (int*)  alloc((NEXP+1)*4);
  int*   topk_idx = (int*)  alloc(NSLOTS*4);
  float* topk_w   = (float*)alloc(NSLOTS*4);
  int*   slot_of  = (int*)  alloc(NSLOTS*4);
  float* gates    = (float*)alloc(TOKENS*4);
  __hip_bfloat16* xb    = (__hip_bfloat16*)alloc((size_t)TOKENS*HDIM*2);
  __hip_bfloat16* xg    = (__hip_bfloat16*)alloc((size_t)(NSLOTS+ROWPAD)*HDIM*2);
  __hip_bfloat16* act   = (__hip_bfloat16*)alloc((size_t)(NSLOTS+ROWPAD)*IDIM*2);
  __hip_bfloat16* shact = (__hip_bfloat16*)alloc((size_t)TOKENS*SIDIM*2);
  float* dslot  = (float*)alloc((size_t)NSLOTS*HDIM*4);
  float* shdown = (float*)alloc((size_t)TOKENS*HDIM*4);
  if ((size_t)(p - (char*)d_ws) > ws_size) return;

  hipMemsetAsync(counts, 0, NEXP*4, stream);
  hipMemsetAsync(fill,   0, NEXP*4, stream);

  router_kernel <<<TOKENS, 64, 0, stream>>>(x, router_w, eg_w, topk_idx, topk_w, gates, counts);
  scatter_kernel<<<TOKENS, 256, 0, stream>>>(x, topk_idx, counts, offsets, fill, slot_of, xg, xb);

  // combined gate+up: 8 XCDs x (22 shared-4m-batched + 165 expert) = 1496 blocks
  gateup_all<<<1496, 256, 64*1024, stream>>>(
      gate_w, up_w, xg, act,
      sh_gate_w, sh_up_w, xb, shact, offsets);

  // combined down: 8 XCDs x (32 shared + 240 expert) = 2176 blocks, 3-deep
  down_all<<<2176, 256, 36*1024, stream>>>(
      down_w, act, dslot,
      sh_down_w, shact, shdown, offsets);

  combine_kernel<<<TOKENS, 256, 0, stream>>>(dslot, shdown, slot_of, topk_w, gates, (float*)d_out);
}